// Round 5
// baseline (59.956 us; speedup 1.0000x reference)
//
#include <hip/hip_runtime.h>
#include <math.h>

#define HH 1024
#define WW 1024
#define BWD 1023   // box-grid width/height (W-1)
#define NBATCH 32
#define NBLK 16    // row-slices per batch
#define ROWS 64    // box rows per slice (16*64=1024 >= 1023)
#define GRID (NBATCH * NBLK)

typedef float f32x4 __attribute__((ext_vector_type(4)));

// Kernel 1: per (batch, row-slice) block, scan 2x2 box sums, local argmax.
// Each thread owns 4 columns; the 5th (neighbor) element comes from
// __shfl_down instead of a second load (wave-boundary lanes keep a
// predicated scalar load). Row loads are non-temporal: each element is
// consumed exactly once.
__global__ __launch_bounds__(256) void cue_scan(const float* __restrict__ cue,
                                                float* __restrict__ wsv,
                                                int* __restrict__ wsi) {
    const int bid = blockIdx.x;
    const int b   = bid / NBLK;
    const int blk = bid % NBLK;
    const int t   = threadIdx.x;      // 0..255
    const int x   = t * 4;            // column chunk base
    const int yStart = blk * ROWS;
    const int yEnd   = min(yStart + ROWS, BWD);
    const float* __restrict__ ch = cue + (size_t)b * 3 * HH * WW;

    const bool haveV4 = (t < 255);         // last chunk has only 3 valid boxes
    const bool waveEdge = ((t & 63) == 63); // lane 63: shfl_down has no source

    // previous raw row
    const float* rowp = ch + (size_t)yStart * WW + x;
    f32x4 vp = __builtin_nontemporal_load((const f32x4*)rowp);
    float vp4 = __shfl_down(vp.x, 1);
    if (waveEdge && haveV4) vp4 = rowp[4];

    // two independent argmax trackers, merged after the loop (min-index
    // tie-break preserves numpy first-occurrence exactly)
    float bestVA = -INFINITY, bestVB = -INFINITY;
    int   bestIA = 0x7fffffff, bestIB = 0x7fffffff;

    #pragma unroll 4
    for (int y = yStart; y < yEnd; ++y) {
        const float* rowc = ch + (size_t)(y + 1) * WW + x;
        f32x4 vc = __builtin_nontemporal_load((const f32x4*)rowc);
        float vc4 = __shfl_down(vc.x, 1);
        if (waveEdge && haveV4) vc4 = rowc[4];

        // exact reference association: ((tl + tr) + bl) + br
        float s0 = ((vp.x + vp.y) + vc.x) + vc.y;
        float s1 = ((vp.y + vp.z) + vc.y) + vc.z;
        float s2 = ((vp.z + vp.w) + vc.z) + vc.w;
        float s3 = ((vp.w + vp4 ) + vc.w) + vc4;

        const int base = y * BWD + x;
        if (s0 > bestVA) { bestVA = s0; bestIA = base;     }
        if (s1 > bestVA) { bestVA = s1; bestIA = base + 1; }
        if (s2 > bestVB) { bestVB = s2; bestIB = base + 2; }
        if (haveV4 && s3 > bestVB) { bestVB = s3; bestIB = base + 3; }

        vp = vc; vp4 = vc4;
    }

    // merge trackers (strict >, tie -> smaller index = first occurrence)
    float bestV = bestVA; int bestI = bestIA;
    if (bestVB > bestV || (bestVB == bestV && bestIB < bestI)) { bestV = bestVB; bestI = bestIB; }

    // block reduce
    __shared__ float sv[256];
    __shared__ int   si[256];
    sv[t] = bestV; si[t] = bestI;
    __syncthreads();
    for (int off = 128; off > 0; off >>= 1) {
        if (t < off) {
            float v2 = sv[t + off]; int i2 = si[t + off];
            if (v2 > sv[t] || (v2 == sv[t] && i2 < si[t])) { sv[t] = v2; si[t] = i2; }
        }
        __syncthreads();
    }
    if (t == 0) { wsv[bid] = sv[0]; wsi[bid] = si[0]; }
}

// Kernel 2: per-batch final reduce over NBLK candidates + gather + write.
__global__ __launch_bounds__(64) void cue_pick(const float* __restrict__ cue,
                                               const float* __restrict__ wsv,
                                               const int* __restrict__ wsi,
                                               float* __restrict__ out) {
    const int b    = blockIdx.x;
    const int lane = threadIdx.x;   // 0..63, one wave

    float v  = -INFINITY;
    int   id = 0x7fffffff;
    if (lane < NBLK) { v = wsv[b * NBLK + lane]; id = wsi[b * NBLK + lane]; }

    #pragma unroll
    for (int off = 32; off > 0; off >>= 1) {
        float v2 = __shfl_down(v, off);
        int   i2 = __shfl_down(id, off);
        if (v2 > v || (v2 == v && i2 < id)) { v = v2; id = i2; }
    }

    if (lane == 0) {
        const int y0 = id / BWD;
        const int x0 = id - y0 * BWD;
        const float* __restrict__ xc = cue + ((size_t)b * 3 + 1) * HH * WW;
        const float* __restrict__ yc = cue + ((size_t)b * 3 + 2) * HH * WW;
        const size_t p = (size_t)y0 * WW + x0;
        // numpy mean order: ((a + b) + c) + d, then /4
        float xm = ((xc[p] + xc[p + 1]) + xc[p + WW]) + xc[p + WW + 1];
        float ym = ((yc[p] + yc[p + 1]) + yc[p + WW]) + yc[p + WW + 1];
        out[b * 3 + 0] = xm * 0.25f;
        out[b * 3 + 1] = ym * 0.25f;
        out[b * 3 + 2] = v  * 0.25f;
    }
}

extern "C" void kernel_launch(void* const* d_in, const int* in_sizes, int n_in,
                              void* d_out, int out_size, void* d_ws, size_t ws_size,
                              hipStream_t stream) {
    const float* cue = (const float*)d_in[0];
    float* out = (float*)d_out;
    float* wsv = (float*)d_ws;
    int*   wsi = (int*)((char*)d_ws + (size_t)GRID * sizeof(float));

    cue_scan<<<GRID, 256, 0, stream>>>(cue, wsv, wsi);
    cue_pick<<<NBATCH, 64, 0, stream>>>(cue, wsv, wsi, out);
}

// Round 6
// 28.161 us; speedup vs baseline: 2.1290x; 2.1290x over previous
//
#include <hip/hip_runtime.h>
#include <math.h>

#define HH 1024
#define WW 1024
#define BWD 1023   // box-grid width/height (W-1)
#define NBATCH 32
#define NBLK 32    // row-slices per batch
#define ROWS 32    // box rows per slice (32*32=1024 >= 1023)

// Kernel 1: per (batch, row-slice) block, scan box sums, find local argmax.
__global__ __launch_bounds__(256) void cue_scan(const float* __restrict__ cue,
                                                float* __restrict__ wsv,
                                                int* __restrict__ wsi) {
    const int bid = blockIdx.x;
    const int b   = bid / NBLK;
    const int blk = bid % NBLK;
    const int t   = threadIdx.x;      // 0..255
    const int x   = t * 4;            // column chunk base
    const int yStart = blk * ROWS;
    const int yEnd   = min(yStart + ROWS, BWD);
    const float* __restrict__ ch = cue + (size_t)b * 3 * HH * WW;

    const bool haveV4 = (t < 255);    // last chunk has only 3 valid boxes

    // previous raw row (5 values per thread); scalar +4 load is an L1 hit
    const float* rowp = ch + (size_t)yStart * WW + x;
    float4 vp  = *(const float4*)rowp;
    float  vp4 = haveV4 ? rowp[4] : 0.0f;

    float bestV = -INFINITY;
    int   bestI = 0x7fffffff;

    for (int y = yStart; y < yEnd; ++y) {
        const float* rowc = ch + (size_t)(y + 1) * WW + x;
        float4 vc  = *(const float4*)rowc;
        float  vc4 = haveV4 ? rowc[4] : 0.0f;

        // exact reference association: ((tl + tr) + bl) + br
        float s0 = ((vp.x + vp.y) + vc.x) + vc.y;
        float s1 = ((vp.y + vp.z) + vc.y) + vc.z;
        float s2 = ((vp.z + vp.w) + vc.z) + vc.w;
        float s3 = ((vp.w + vp4 ) + vc.w) + vc4;

        const int base = y * BWD + x;
        if (s0 > bestV) { bestV = s0; bestI = base;     }
        if (s1 > bestV) { bestV = s1; bestI = base + 1; }
        if (s2 > bestV) { bestV = s2; bestI = base + 2; }
        if (haveV4 && s3 > bestV) { bestV = s3; bestI = base + 3; }

        vp = vc; vp4 = vc4;
    }

    // block reduce (max value, tie -> smaller index = first occurrence)
    __shared__ float sv[256];
    __shared__ int   si[256];
    sv[t] = bestV; si[t] = bestI;
    __syncthreads();
    for (int off = 128; off > 0; off >>= 1) {
        if (t < off) {
            float v2 = sv[t + off]; int i2 = si[t + off];
            if (v2 > sv[t] || (v2 == sv[t] && i2 < si[t])) { sv[t] = v2; si[t] = i2; }
        }
        __syncthreads();
    }
    if (t == 0) { wsv[bid] = sv[0]; wsi[bid] = si[0]; }
}

// Kernel 2: per-batch final reduce over NBLK candidates + gather + write.
__global__ __launch_bounds__(64) void cue_pick(const float* __restrict__ cue,
                                               const float* __restrict__ wsv,
                                               const int* __restrict__ wsi,
                                               float* __restrict__ out) {
    const int b    = blockIdx.x;
    const int lane = threadIdx.x;   // 0..63, one wave

    float v  = -INFINITY;
    int   id = 0x7fffffff;
    if (lane < NBLK) { v = wsv[b * NBLK + lane]; id = wsi[b * NBLK + lane]; }

    #pragma unroll
    for (int off = 32; off > 0; off >>= 1) {
        float v2 = __shfl_down(v, off);
        int   i2 = __shfl_down(id, off);
        if (v2 > v || (v2 == v && i2 < id)) { v = v2; id = i2; }
    }

    if (lane == 0) {
        const int y0 = id / BWD;
        const int x0 = id - y0 * BWD;
        const float* __restrict__ xc = cue + ((size_t)b * 3 + 1) * HH * WW;
        const float* __restrict__ yc = cue + ((size_t)b * 3 + 2) * HH * WW;
        const size_t p = (size_t)y0 * WW + x0;
        // numpy mean order: ((a + b) + c) + d, then /4
        float xm = ((xc[p] + xc[p + 1]) + xc[p + WW]) + xc[p + WW + 1];
        float ym = ((yc[p] + yc[p + 1]) + yc[p + WW]) + yc[p + WW + 1];
        out[b * 3 + 0] = xm * 0.25f;
        out[b * 3 + 1] = ym * 0.25f;
        out[b * 3 + 2] = v  * 0.25f;
    }
}

extern "C" void kernel_launch(void* const* d_in, const int* in_sizes, int n_in,
                              void* d_out, int out_size, void* d_ws, size_t ws_size,
                              hipStream_t stream) {
    const float* cue = (const float*)d_in[0];
    float* out = (float*)d_out;
    float* wsv = (float*)d_ws;
    int*   wsi = (int*)((char*)d_ws + (size_t)NBATCH * NBLK * sizeof(float));

    cue_scan<<<NBATCH * NBLK, 256, 0, stream>>>(cue, wsv, wsi);
    cue_pick<<<NBATCH, 64, 0, stream>>>(cue, wsv, wsi, out);
}